// Round 8
// baseline (961.796 us; speedup 1.0000x reference)
//
#include <hip/hip_runtime.h>

#define LNUM 4
#define DMODEL 1024
#define NHEAD 16
#define FDIM 4096
#define BATCH 4
#define SEQ 1024
#define HDIM 64
#define KBAND 8
#define MROWS (BATCH * SEQ)

typedef __attribute__((ext_vector_type(8))) __bf16 bf16x8;
typedef __attribute__((ext_vector_type(4))) float f32x4;

__device__ __forceinline__ unsigned short f2bf(float f) {
  unsigned int u = __builtin_bit_cast(unsigned int, f);
  u = u + 0x7fffu + ((u >> 16) & 1u);
  return (unsigned short)(u >> 16);
}
__device__ __forceinline__ float bf2f(unsigned short h) {
  unsigned int u = ((unsigned int)h) << 16;
  return __builtin_bit_cast(float, u);
}

#define GLOAD16(gp, lp)                                                        \
  __builtin_amdgcn_global_load_lds(                                            \
      (const __attribute__((address_space(1))) void*)(gp),                     \
      (__attribute__((address_space(3))) void*)(lp), 16, 0, 0)

// ---------------- fp32 -> bf16 conversion -----------------------------------
__global__ __launch_bounds__(256) void cvt_bf16(const float* __restrict__ in,
                                                unsigned short* __restrict__ out,
                                                long n) {
  long i = ((long)blockIdx.x * 256 + threadIdx.x) * 4;
  if (i + 3 < n) {
    float4 v = *reinterpret_cast<const float4*>(in + i);
    ushort4 o;
    o.x = f2bf(v.x);
    o.y = f2bf(v.y);
    o.z = f2bf(v.z);
    o.w = f2bf(v.w);
    *reinterpret_cast<ushort4*>(out + i) = o;
  }
}

// ---------------- 128x128 m97-structure bf16 GEMM, C = A * W^T + bias -------
// A: [M,K] bf16 rm. W: [N,K] bf16 rm. 256 thr = 4 waves (2x2), per-wave
// 64x64 out (acc 4x4 f32x4). BK=32, SINGLE-buffer 16KB LDS:
//   stage (4 gload_lds) -> sync -> 8 ds_read + 16 MFMA -> sync.
// Latency hiding comes from 3-4 resident blocks/CU (TLP, m114/m97-regime),
// NOT in-block pipelining — that's the structure's verified 833-912 TF
// operating point (m102/m103). 1-block/CU 256^2 schedules all plateaued
// at 370-460 TF in R3-R7.
// T2 granule swizzle for BK=32 (64B rows): LDS granule (row,gc) holds
// global col-granule gc^(row&3); write side = pre-swizzled global source
// (per-lane addr), read side = same XOR. Residual 2-way conflict is free
// (m136). XCD swizzle: bijective m204 chunked, bm-fastest.
// blockIdx.z = K-split (range [z*Ks,(z+1)*Ks)); Ks % 32 == 0.
// EPI: 0 = bf16 (+bias), 1 = bf16 (+bias, exact gelu),
//      2 = bf16 PARTIAL slab per z (bias only z==0).
template <int EPI>
__global__ __launch_bounds__(256, 3) void gemm128(const unsigned short* __restrict__ A,
                                                  const unsigned short* __restrict__ W,
                                                  const float* __restrict__ bias,
                                                  unsigned short* __restrict__ Cout,
                                                  int Ndim, int Kdim, int Ks) {
  __shared__ unsigned short As[4096];  // 128r x 32k, granule-swizzled
  __shared__ unsigned short Bs[4096];
  const int tid = threadIdx.x;
  const int wave = tid >> 6;
  const int lane = tid & 63;

  // bijective XCD chunked swizzle (m204), bm-fastest within chunk: each
  // XCD's B (weight) slab stays L2-resident while A streams via L3.
  const int gx = gridDim.x, gy = gridDim.y;
  const int nwg = gx * gy;
  const int lin = blockIdx.x + blockIdx.y * gx;
  const int q8 = nwg >> 3, r8 = nwg & 7;
  const int xcd = lin & 7, cidx = lin >> 3;
  const int cbase = (xcd < r8) ? xcd * (q8 + 1) : r8 * (q8 + 1) + (xcd - r8) * q8;
  const int swz = cbase + cidx;
  const int bm0 = (swz % gy) * 128;
  const int bn0 = (swz / gy) * 128;
  const int kz0 = blockIdx.z * Ks;

  // staging: tile 128r x 32k = 8KB/matrix = 256 thr x 2 instrs x 16B.
  // instr granule (16B) for thread t: rows t>>2 (+64 for instr 2), gc = t&3;
  // pre-swizzled global source col-granule = gc ^ (row&3).
  const int r0 = tid >> 2;                              // 0..63
  const int c0 = (((tid & 3) ^ ((tid >> 2) & 3)) << 3); // swizzled col elem
  const unsigned short* gA = A + (size_t)(bm0 + r0) * Kdim + kz0 + c0;
  const unsigned short* gB = W + (size_t)(bn0 + r0) * Kdim + kz0 + c0;
  const size_t rowstep = (size_t)64 * Kdim;

  f32x4 acc[4][4] = {};

  const int wr = (wave >> 1) * 64;  // wave row origin in tile
  const int wc = (wave & 1) * 64;   // wave col origin in tile
  const int fr = lane & 15;
  const int kg = lane >> 4;                  // K granule 0..3
  const int kofs = ((kg ^ (fr & 3)) << 3);   // read-side swizzled col elem

  const int nt = Ks >> 5;
  for (int t = 0; t < nt; ++t) {
    GLOAD16(gA, &As[wave * 512]);
    GLOAD16(gA + rowstep, &As[2048 + wave * 512]);
    GLOAD16(gB, &Bs[wave * 512]);
    GLOAD16(gB + rowstep, &Bs[2048 + wave * 512]);
    gA += 32;
    gB += 32;
    __syncthreads();  // drains vmcnt(0): tile staged
    bf16x8 af[4], bfr[4];
#pragma unroll
    for (int i = 0; i < 4; ++i)
      af[i] = *reinterpret_cast<const bf16x8*>(&As[(wr + i * 16 + fr) * 32 + kofs]);
#pragma unroll
    for (int j = 0; j < 4; ++j)
      bfr[j] = *reinterpret_cast<const bf16x8*>(&Bs[(wc + j * 16 + fr) * 32 + kofs]);
#pragma unroll
    for (int i = 0; i < 4; ++i)
#pragma unroll
      for (int j = 0; j < 4; ++j)
        acc[i][j] = __builtin_amdgcn_mfma_f32_16x16x32_bf16(af[i], bfr[j], acc[i][j], 0, 0, 0);
    __syncthreads();  // reads done before next stage overwrites
  }

  // epilogue: C/D layout col=lane&15, row=(lane>>4)*4+reg (m89/m91)
  const int rr = (lane >> 4) * 4;
  const int cc = lane & 15;
  const bool addb = (EPI != 2) || (blockIdx.z == 0);
  unsigned short* outZ =
      Cout + (EPI == 2 ? (size_t)blockIdx.z * ((size_t)gy * 128) * Ndim : 0);
#pragma unroll
  for (int j = 0; j < 4; ++j) {
    const int n = bn0 + wc + j * 16 + cc;
    const float bv = addb ? bias[n] : 0.0f;
#pragma unroll
    for (int i = 0; i < 4; ++i) {
#pragma unroll
      for (int r = 0; r < 4; ++r) {
        const int m = bm0 + wr + i * 16 + rr + r;
        float v = acc[i][j][r] + bv;
        if (EPI == 1) v = 0.5f * v * (1.0f + erff(v * 0.70710678118654752f));
        outZ[(size_t)m * Ndim + n] = f2bf(v);
      }
    }
  }
}

// ---------------- banded attention: one wave per (b,h,q), lane = d ----------
__global__ __launch_bounds__(256) void attn_band(const unsigned short* __restrict__ qkv,
                                                 unsigned short* __restrict__ outp) {
  const int gw = blockIdx.x * 4 + (threadIdx.x >> 6);
  const int lane = threadIdx.x & 63;
  const int q = gw & (SEQ - 1);
  const int bh = gw >> 10;
  const int h = bh & (NHEAD - 1);
  const int b = bh >> 4;
  const size_t row0 = (size_t)(b * SEQ + q);
  const size_t stride = 3 * DMODEL;
  const float qv = bf2f(qkv[row0 * stride + h * HDIM + lane]);

  float sc[KBAND];
  float mx = -1e30f;
#pragma unroll
  for (int jj = 0; jj < KBAND; ++jj) {
    const int j = q + jj;
    const int jc = (j < SEQ) ? j : (SEQ - 1);
    float kv = bf2f(qkv[(size_t)(b * SEQ + jc) * stride + DMODEL + h * HDIM + lane]);
    float p = qv * kv;
#pragma unroll
    for (int m = 32; m; m >>= 1) p += __shfl_xor(p, m);
    p *= 0.125f;
    p = (j < SEQ) ? p : -1e30f;
    sc[jj] = p;
    mx = fmaxf(mx, p);
  }
  float denom = 0.f;
  float ov = 0.f;
#pragma unroll
  for (int jj = 0; jj < KBAND; ++jj) {
    const int j = q + jj;
    const int jc = (j < SEQ) ? j : (SEQ - 1);
    float p = __expf(sc[jj] - mx);
    p = (j < SEQ) ? p : 0.f;
    denom += p;
    ov += p * bf2f(qkv[(size_t)(b * SEQ + jc) * stride + 2 * DMODEL + h * HDIM + lane]);
  }
  ov /= denom;
  outp[row0 * DMODEL + h * HDIM + lane] = f2bf(ov);
}

// ---------------- residual + 2-way bf16 split-K reduce + LayerNorm ----------
__global__ __launch_bounds__(256) void add_ln2(const float* __restrict__ resid,
                                               const unsigned short* __restrict__ part,
                                               const float* __restrict__ gw,
                                               const float* __restrict__ gb,
                                               float* __restrict__ xf,
                                               unsigned short* __restrict__ xb) {
  const int row = blockIdx.x;
  const int tid = threadIdx.x;
  const size_t slab = (size_t)MROWS * DMODEL;
  const float* rp = resid + (size_t)row * DMODEL;
  const unsigned short* pp = part + (size_t)row * DMODEL;
  float v[4];
  float s = 0.f, s2 = 0.f;
#pragma unroll
  for (int i = 0; i < 4; ++i) {
    const int idx = tid + i * 256;
    float a = rp[idx] + bf2f(pp[idx]) + bf2f(pp[slab + idx]);
    v[i] = a;
    s += a;
    s2 += a * a;
  }
#pragma unroll
  for (int m = 32; m; m >>= 1) {
    s += __shfl_xor(s, m);
    s2 += __shfl_xor(s2, m);
  }
  __shared__ float wsm[8];
  const int wave = tid >> 6, lane = tid & 63;
  if (lane == 0) {
    wsm[wave] = s;
    wsm[4 + wave] = s2;
  }
  __syncthreads();
  s = wsm[0] + wsm[1] + wsm[2] + wsm[3];
  s2 = wsm[4] + wsm[5] + wsm[6] + wsm[7];
  const float mean = s * (1.f / DMODEL);
  const float var = s2 * (1.f / DMODEL) - mean * mean;
  const float rstd = rsqrtf(var + 1e-5f);
#pragma unroll
  for (int i = 0; i < 4; ++i) {
    const int idx = tid + i * 256;
    const float y = (v[i] - mean) * rstd * gw[idx] + gb[idx];
    xf[(size_t)row * DMODEL + idx] = y;
    xb[(size_t)row * DMODEL + idx] = f2bf(y);
  }
}

extern "C" void kernel_launch(void* const* d_in, const int* in_sizes, int n_in,
                              void* d_out, int out_size, void* d_ws, size_t ws_size,
                              hipStream_t stream) {
  const float* src  = (const float*)d_in[0];
  const float* Wqkv = (const float*)d_in[1];
  const float* bqkv = (const float*)d_in[2];
  const float* Wo   = (const float*)d_in[3];
  const float* bo   = (const float*)d_in[4];
  const float* W1   = (const float*)d_in[5];
  const float* b1   = (const float*)d_in[6];
  const float* W2   = (const float*)d_in[7];
  const float* b2   = (const float*)d_in[8];
  const float* ln1w = (const float*)d_in[9];
  const float* ln1b = (const float*)d_in[10];
  const float* ln2w = (const float*)d_in[11];
  const float* ln2b = (const float*)d_in[12];
  float* out = (float*)d_out;

  // workspace carve-up (~177 MB of 209.7 MB)
  char* p = (char*)d_ws;
  unsigned short* wqkv_b = (unsigned short*)p; p += (size_t)LNUM * 3072 * 1024 * 2;
  unsigned short* wo_b   = (unsigned short*)p; p += (size_t)LNUM * 1024 * 1024 * 2;
  unsigned short* w1_b   = (unsigned short*)p; p += (size_t)LNUM * 4096 * 1024 * 2;
  unsigned short* w2_b   = (unsigned short*)p; p += (size_t)LNUM * 1024 * 4096 * 2;
  float*          xf     = (float*)p;          p += (size_t)MROWS * DMODEL * 4;
  unsigned short* xb     = (unsigned short*)p; p += (size_t)MROWS * DMODEL * 2;
  // region R: [qkvb 24MB | aob 8MB] aliased by [hb 32MB], then part 2x8MB bf16
  char* R = p;
  unsigned short* qkvb = (unsigned short*)R;
  unsigned short* aob  = (unsigned short*)(R + (size_t)MROWS * 3 * DMODEL * 2);
  unsigned short* hb   = (unsigned short*)R;
  unsigned short* part = (unsigned short*)(R + (size_t)MROWS * 4096 * 2);
  p = R + (size_t)MROWS * 4096 * 2 + (size_t)2 * MROWS * DMODEL * 2;
  if (ws_size < (size_t)(p - (char*)d_ws)) return;

  cvt_bf16<<<(long)LNUM * 3072 * 1024 / 1024, 256, 0, stream>>>(Wqkv, wqkv_b, (long)LNUM * 3072 * 1024);
  cvt_bf16<<<(long)LNUM * 1024 * 1024 / 1024, 256, 0, stream>>>(Wo, wo_b, (long)LNUM * 1024 * 1024);
  cvt_bf16<<<(long)LNUM * 4096 * 1024 / 1024, 256, 0, stream>>>(W1, w1_b, (long)LNUM * 4096 * 1024);
  cvt_bf16<<<(long)LNUM * 1024 * 4096 / 1024, 256, 0, stream>>>(W2, w2_b, (long)LNUM * 1024 * 4096);
  cvt_bf16<<<(long)MROWS * DMODEL / 1024, 256, 0, stream>>>(src, xb, (long)MROWS * DMODEL);

  for (int l = 0; l < LNUM; ++l) {
    // QKV: [4096,1024] x [3072,1024]^T -> bf16 [4096,3072]; 768 blk (3/CU)
    gemm128<0><<<dim3(3072 / 128, MROWS / 128, 1), 256, 0, stream>>>(
        xb, wqkv_b + (size_t)l * 3072 * 1024, bqkv + l * 3072, qkvb, 3072, 1024, 1024);
    attn_band<<<(BATCH * NHEAD * SEQ) / 4, 256, 0, stream>>>(qkvb, aob);
    // Wo: split-K=2 (Ks=512) -> bf16 partials; 512 blk (2/CU)
    gemm128<2><<<dim3(1024 / 128, MROWS / 128, 2), 256, 0, stream>>>(
        aob, wo_b + (size_t)l * 1024 * 1024, bo + l * 1024, part, 1024, 1024, 512);
    add_ln2<<<MROWS, 256, 0, stream>>>(l == 0 ? src : xf, part,
                                       ln1w + l * DMODEL, ln1b + l * DMODEL, xf, xb);
    // W1 + gelu: -> bf16 [4096,4096]; 1024 blk (4/CU)
    gemm128<1><<<dim3(FDIM / 128, MROWS / 128, 1), 256, 0, stream>>>(
        xb, w1_b + (size_t)l * 4096 * 1024, b1 + l * FDIM, hb, FDIM, 1024, 1024);
    // W2: split-K=2 (Ks=2048) -> bf16 partials; 512 blk (2/CU)
    gemm128<2><<<dim3(1024 / 128, MROWS / 128, 2), 256, 0, stream>>>(
        hb, w2_b + (size_t)l * 1024 * 4096, b2 + l * 1024, part, 1024, 4096, 2048);
    float* dst = (l == LNUM - 1) ? out : xf;
    add_ln2<<<MROWS, 256, 0, stream>>>(xf, part,
                                       ln2w + l * DMODEL, ln2b + l * DMODEL, dst, xb);
  }
}

// Round 9
// 942.472 us; speedup vs baseline: 1.0205x; 1.0205x over previous
//
#include <hip/hip_runtime.h>

#define LNUM 4
#define DMODEL 1024
#define NHEAD 16
#define FDIM 4096
#define BATCH 4
#define SEQ 1024
#define HDIM 64
#define KBAND 8
#define MROWS (BATCH * SEQ)

typedef __attribute__((ext_vector_type(8))) __bf16 bf16x8;
typedef __attribute__((ext_vector_type(4))) float f32x4;
typedef __attribute__((ext_vector_type(8))) unsigned short u16x8;

__device__ __forceinline__ unsigned short f2bf(float f) {
  unsigned int u = __builtin_bit_cast(unsigned int, f);
  u = u + 0x7fffu + ((u >> 16) & 1u);
  return (unsigned short)(u >> 16);
}
__device__ __forceinline__ float bf2f(unsigned short h) {
  unsigned int u = ((unsigned int)h) << 16;
  return __builtin_bit_cast(float, u);
}

#define GLOAD16(gp, lp)                                                        \
  __builtin_amdgcn_global_load_lds(                                            \
      (const __attribute__((address_space(1))) void*)(gp),                     \
      (__attribute__((address_space(3))) void*)(lp), 16, 0, 0)

// ---------------- fp32 -> bf16 conversion -----------------------------------
__global__ __launch_bounds__(256) void cvt_bf16(const float* __restrict__ in,
                                                unsigned short* __restrict__ out,
                                                long n) {
  long i = ((long)blockIdx.x * 256 + threadIdx.x) * 4;
  if (i + 3 < n) {
    float4 v = *reinterpret_cast<const float4*>(in + i);
    ushort4 o;
    o.x = f2bf(v.x);
    o.y = f2bf(v.y);
    o.z = f2bf(v.z);
    o.w = f2bf(v.w);
    *reinterpret_cast<ushort4*>(out + i) = o;
  }
}

// ---------------- 128x128 m97-structure bf16 GEMM, C = A * W^T + bias -------
// A: [M,K] bf16 rm. W: [N,K] bf16 rm. 256 thr = 4 waves (2x2), per-wave
// 64x64 out (acc 4x4 f32x4). BK=32, single-buffer 16KB LDS, TLP-hiding
// (3-4 blocks/CU). T2 granule swizzle FIXED (R8 had 4.2M conflicts):
//   stored (row, g) holds global col-granule g ^ ((row>>1)&3).
//   Read quad = (fr&1)*4 + (kg^((fr>>1)&3)): quarter-wave covers all 8
//   quads 2x each = conflict-free minimum. Write side pre-swizzles the
//   global source col (linear gload_lds dest, rule #21).
// Epilogue: wave-private LDS transpose in 32x32 quarters (u16, stride-40
//   rows): stage writes 2/bank, b128 reads hit each quad exactly 2x
//   (both = free); lane-pair emits one full 64B line per output row ->
//   1.0x write amplification, 8 dwordx4 stores/thread (was 64x 2B).
// blockIdx.z = K-split (range [z*Ks,(z+1)*Ks)); Ks % 32 == 0.
// EPI: 0 = bf16 (+bias), 1 = bf16 (+bias, exact gelu),
//      2 = bf16 PARTIAL slab per z (bias only z==0).
template <int EPI>
__global__ __launch_bounds__(256, 3) void gemm128(const unsigned short* __restrict__ A,
                                                  const unsigned short* __restrict__ W,
                                                  const float* __restrict__ bias,
                                                  unsigned short* __restrict__ Cout,
                                                  int Ndim, int Kdim, int Ks) {
  __shared__ unsigned short SH[8192];  // As=SH[0:4096], Bs=SH[4096:8192]
  unsigned short* As = SH;
  unsigned short* Bs = SH + 4096;
  const int tid = threadIdx.x;
  const int wave = tid >> 6;
  const int lane = tid & 63;

  // bijective XCD chunked swizzle (m204), bm-fastest within chunk.
  const int gx = gridDim.x, gy = gridDim.y;
  const int nwg = gx * gy;
  const int lin = blockIdx.x + blockIdx.y * gx;
  const int q8 = nwg >> 3, r8 = nwg & 7;
  const int xcd = lin & 7, cidx = lin >> 3;
  const int cbase = (xcd < r8) ? xcd * (q8 + 1) : r8 * (q8 + 1) + (xcd - r8) * q8;
  const int swz = cbase + cidx;
  const int bm0 = (swz % gy) * 128;
  const int bn0 = (swz / gy) * 128;
  const int kz0 = blockIdx.z * Ks;

  // staging: tile 128r x 32k = 8KB/matrix = 256 thr x 2 instrs x 16B.
  // thread t -> row t>>2, LDS granule t&3; source granule (t&3)^((t>>3)&3)
  // (key (row>>1)&3; row+64 for instr 2 leaves the key unchanged).
  const int r0 = tid >> 2;
  const int c0 = (((tid & 3) ^ ((tid >> 3) & 3)) << 3);
  const unsigned short* gA = A + (size_t)(bm0 + r0) * Kdim + kz0 + c0;
  const unsigned short* gB = W + (size_t)(bn0 + r0) * Kdim + kz0 + c0;
  const size_t rowstep = (size_t)64 * Kdim;

  f32x4 acc[4][4] = {};

  const int wr = (wave >> 1) * 64;  // wave row origin in tile
  const int wc = (wave & 1) * 64;   // wave col origin in tile
  const int fr = lane & 15;
  const int kg = lane >> 4;                        // K granule 0..3
  const int kofs = ((kg ^ ((fr >> 1) & 3)) << 3);  // read-side swizzled col

  const int nt = Ks >> 5;
  for (int t = 0; t < nt; ++t) {
    GLOAD16(gA, &As[wave * 512]);
    GLOAD16(gA + rowstep, &As[2048 + wave * 512]);
    GLOAD16(gB, &Bs[wave * 512]);
    GLOAD16(gB + rowstep, &Bs[2048 + wave * 512]);
    gA += 32;
    gB += 32;
    __syncthreads();  // drains vmcnt(0): tile staged
    bf16x8 af[4], bfr[4];
#pragma unroll
    for (int i = 0; i < 4; ++i)
      af[i] = *reinterpret_cast<const bf16x8*>(&As[(wr + i * 16 + fr) * 32 + kofs]);
#pragma unroll
    for (int j = 0; j < 4; ++j)
      bfr[j] = *reinterpret_cast<const bf16x8*>(&Bs[(wc + j * 16 + fr) * 32 + kofs]);
#pragma unroll
    for (int i = 0; i < 4; ++i)
#pragma unroll
      for (int j = 0; j < 4; ++j)
        acc[i][j] = __builtin_amdgcn_mfma_f32_16x16x32_bf16(af[i], bfr[j], acc[i][j], 0, 0, 0);
    __syncthreads();  // reads done before next stage overwrites
  }

  // ---- transposed epilogue (after final syncthreads; LDS reused) ----
  // C/D layout: col = lane&15, row = (lane>>4)*4 + reg (m89/m91).
  const int rr = (lane >> 4) * 4;
  const int cc = lane & 15;
  const bool addb = (EPI != 2) || (blockIdx.z == 0);
  unsigned short* outZ =
      Cout + (EPI == 2 ? (size_t)blockIdx.z * ((size_t)gy * 128) * Ndim : 0);
  float bv[4];
#pragma unroll
  for (int j = 0; j < 4; ++j)
    bv[j] = addb ? bias[bn0 + wc + j * 16 + cc] : 0.0f;

  unsigned short* lt = SH + wave * 1280;  // 2560 B per wave (32 rows x 40 u16)
#pragma unroll
  for (int rh = 0; rh < 2; ++rh) {        // row half: rows rh*32..+31
#pragma unroll
    for (int cp = 0; cp < 2; ++cp) {      // col pair: cols cp*32..+31
#pragma unroll
      for (int ii = 0; ii < 2; ++ii)
#pragma unroll
        for (int jj = 0; jj < 2; ++jj)
#pragma unroll
          for (int r = 0; r < 4; ++r) {
            float v = acc[rh * 2 + ii][cp * 2 + jj][r] + bv[cp * 2 + jj];
            if (EPI == 1) v = 0.5f * v * (1.0f + erff(v * 0.70710678118654752f));
            lt[(ii * 16 + rr + r) * 40 + jj * 16 + cc] = f2bf(v);
          }
      asm volatile("s_waitcnt lgkmcnt(0)" ::: "memory");  // wave-local RAW
      const int rl = lane >> 1;            // local row 0..31
      const int chalf = (lane & 1) * 16;   // col sub-half (16 u16 = 32 B)
      u16x8 o0 = *reinterpret_cast<const u16x8*>(&lt[rl * 40 + chalf]);
      u16x8 o1 = *reinterpret_cast<const u16x8*>(&lt[rl * 40 + chalf + 8]);
      const int m = bm0 + wr + rh * 32 + rl;
      const int n0 = bn0 + wc + cp * 32 + chalf;
      unsigned short* dst = outZ + (size_t)m * Ndim + n0;
      *reinterpret_cast<u16x8*>(dst) = o0;
      *reinterpret_cast<u16x8*>(dst + 8) = o1;
      asm volatile("s_waitcnt lgkmcnt(0)" ::: "memory");  // reads done pre-overwrite
    }
  }
}

// ---------------- banded attention: one wave per (b,h,q), lane = d ----------
__global__ __launch_bounds__(256) void attn_band(const unsigned short* __restrict__ qkv,
                                                 unsigned short* __restrict__ outp) {
  const int gw = blockIdx.x * 4 + (threadIdx.x >> 6);
  const int lane = threadIdx.x & 63;
  const int q = gw & (SEQ - 1);
  const int bh = gw >> 10;
  const int h = bh & (NHEAD - 1);
  const int b = bh >> 4;
  const size_t row0 = (size_t)(b * SEQ + q);
  const size_t stride = 3 * DMODEL;
  const float qv = bf2f(qkv[row0 * stride + h * HDIM + lane]);

  float sc[KBAND];
  float mx = -1e30f;
#pragma unroll
  for (int jj = 0; jj < KBAND; ++jj) {
    const int j = q + jj;
    const int jc = (j < SEQ) ? j : (SEQ - 1);
    float kv = bf2f(qkv[(size_t)(b * SEQ + jc) * stride + DMODEL + h * HDIM + lane]);
    float p = qv * kv;
#pragma unroll
    for (int m = 32; m; m >>= 1) p += __shfl_xor(p, m);
    p *= 0.125f;
    p = (j < SEQ) ? p : -1e30f;
    sc[jj] = p;
    mx = fmaxf(mx, p);
  }
  float denom = 0.f;
  float ov = 0.f;
#pragma unroll
  for (int jj = 0; jj < KBAND; ++jj) {
    const int j = q + jj;
    const int jc = (j < SEQ) ? j : (SEQ - 1);
    float p = __expf(sc[jj] - mx);
    p = (j < SEQ) ? p : 0.f;
    denom += p;
    ov += p * bf2f(qkv[(size_t)(b * SEQ + jc) * stride + 2 * DMODEL + h * HDIM + lane]);
  }
  ov /= denom;
  outp[row0 * DMODEL + h * HDIM + lane] = f2bf(ov);
}

// ---------------- residual + 2-way bf16 split-K reduce + LayerNorm ----------
__global__ __launch_bounds__(256) void add_ln2(const float* __restrict__ resid,
                                               const unsigned short* __restrict__ part,
                                               const float* __restrict__ gw,
                                               const float* __restrict__ gb,
                                               float* __restrict__ xf,
                                               unsigned short* __restrict__ xb) {
  const int row = blockIdx.x;
  const int tid = threadIdx.x;
  const size_t slab = (size_t)MROWS * DMODEL;
  const float* rp = resid + (size_t)row * DMODEL;
  const unsigned short* pp = part + (size_t)row * DMODEL;
  float v[4];
  float s = 0.f, s2 = 0.f;
#pragma unroll
  for (int i = 0; i < 4; ++i) {
    const int idx = tid + i * 256;
    float a = rp[idx] + bf2f(pp[idx]) + bf2f(pp[slab + idx]);
    v[i] = a;
    s += a;
    s2 += a * a;
  }
#pragma unroll
  for (int m = 32; m; m >>= 1) {
    s += __shfl_xor(s, m);
    s2 += __shfl_xor(s2, m);
  }
  __shared__ float wsm[8];
  const int wave = tid >> 6, lane = tid & 63;
  if (lane == 0) {
    wsm[wave] = s;
    wsm[4 + wave] = s2;
  }
  __syncthreads();
  s = wsm[0] + wsm[1] + wsm[2] + wsm[3];
  s2 = wsm[4] + wsm[5] + wsm[6] + wsm[7];
  const float mean = s * (1.f / DMODEL);
  const float var = s2 * (1.f / DMODEL) - mean * mean;
  const float rstd = rsqrtf(var + 1e-5f);
#pragma unroll
  for (int i = 0; i < 4; ++i) {
    const int idx = tid + i * 256;
    const float y = (v[i] - mean) * rstd * gw[idx] + gb[idx];
    xf[(size_t)row * DMODEL + idx] = y;
    xb[(size_t)row * DMODEL + idx] = f2bf(y);
  }
}

extern "C" void kernel_launch(void* const* d_in, const int* in_sizes, int n_in,
                              void* d_out, int out_size, void* d_ws, size_t ws_size,
                              hipStream_t stream) {
  const float* src  = (const float*)d_in[0];
  const float* Wqkv = (const float*)d_in[1];
  const float* bqkv = (const float*)d_in[2];
  const float* Wo   = (const float*)d_in[3];
  const float* bo   = (const float*)d_in[4];
  const float* W1   = (const float*)d_in[5];
  const float* b1   = (const float*)d_in[6];
  const float* W2   = (const float*)d_in[7];
  const float* b2   = (const float*)d_in[8];
  const float* ln1w = (const float*)d_in[9];
  const float* ln1b = (const float*)d_in[10];
  const float* ln2w = (const float*)d_in[11];
  const float* ln2b = (const float*)d_in[12];
  float* out = (float*)d_out;

  // workspace carve-up (~177 MB of 209.7 MB)
  char* p = (char*)d_ws;
  unsigned short* wqkv_b = (unsigned short*)p; p += (size_t)LNUM * 3072 * 1024 * 2;
  unsigned short* wo_b   = (unsigned short*)p; p += (size_t)LNUM * 1024 * 1024 * 2;
  unsigned short* w1_b   = (unsigned short*)p; p += (size_t)LNUM * 4096 * 1024 * 2;
  unsigned short* w2_b   = (unsigned short*)p; p += (size_t)LNUM * 1024 * 4096 * 2;
  float*          xf     = (float*)p;          p += (size_t)MROWS * DMODEL * 4;
  unsigned short* xb     = (unsigned short*)p; p += (size_t)MROWS * DMODEL * 2;
  // region R: [qkvb 24MB | aob 8MB] aliased by [hb 32MB], then part 2x8MB bf16
  char* R = p;
  unsigned short* qkvb = (unsigned short*)R;
  unsigned short* aob  = (unsigned short*)(R + (size_t)MROWS * 3 * DMODEL * 2);
  unsigned short* hb   = (unsigned short*)R;
  unsigned short* part = (unsigned short*)(R + (size_t)MROWS * 4096 * 2);
  p = R + (size_t)MROWS * 4096 * 2 + (size_t)2 * MROWS * DMODEL * 2;
  if (ws_size < (size_t)(p - (char*)d_ws)) return;

  cvt_bf16<<<(long)LNUM * 3072 * 1024 / 1024, 256, 0, stream>>>(Wqkv, wqkv_b, (long)LNUM * 3072 * 1024);
  cvt_bf16<<<(long)LNUM * 1024 * 1024 / 1024, 256, 0, stream>>>(Wo, wo_b, (long)LNUM * 1024 * 1024);
  cvt_bf16<<<(long)LNUM * 4096 * 1024 / 1024, 256, 0, stream>>>(W1, w1_b, (long)LNUM * 4096 * 1024);
  cvt_bf16<<<(long)LNUM * 1024 * 4096 / 1024, 256, 0, stream>>>(W2, w2_b, (long)LNUM * 1024 * 4096);
  cvt_bf16<<<(long)MROWS * DMODEL / 1024, 256, 0, stream>>>(src, xb, (long)MROWS * DMODEL);

  for (int l = 0; l < LNUM; ++l) {
    // QKV: [4096,1024] x [3072,1024]^T -> bf16 [4096,3072]; 768 blk (3/CU)
    gemm128<0><<<dim3(3072 / 128, MROWS / 128, 1), 256, 0, stream>>>(
        xb, wqkv_b + (size_t)l * 3072 * 1024, bqkv + l * 3072, qkvb, 3072, 1024, 1024);
    attn_band<<<(BATCH * NHEAD * SEQ) / 4, 256, 0, stream>>>(qkvb, aob);
    // Wo: split-K=2 (Ks=512) -> bf16 partials; 512 blk (2/CU)
    gemm128<2><<<dim3(1024 / 128, MROWS / 128, 2), 256, 0, stream>>>(
        aob, wo_b + (size_t)l * 1024 * 1024, bo + l * 1024, part, 1024, 1024, 512);
    add_ln2<<<MROWS, 256, 0, stream>>>(l == 0 ? src : xf, part,
                                       ln1w + l * DMODEL, ln1b + l * DMODEL, xf, xb);
    // W1 + gelu: -> bf16 [4096,4096]; 1024 blk (4/CU)
    gemm128<1><<<dim3(FDIM / 128, MROWS / 128, 1), 256, 0, stream>>>(
        xb, w1_b + (size_t)l * 4096 * 1024, b1 + l * FDIM, hb, FDIM, 1024, 1024);
    // W2: split-K=2 (Ks=2048) -> bf16 partials; 512 blk (2/CU)
    gemm128<2><<<dim3(1024 / 128, MROWS / 128, 2), 256, 0, stream>>>(
        hb, w2_b + (size_t)l * 1024 * 4096, b2 + l * 1024, part, 1024, 4096, 2048);
    float* dst = (l == LNUM - 1) ? out : xf;
    add_ln2<<<MROWS, 256, 0, stream>>>(xf, part,
                                       ln2w + l * DMODEL, ln2b + l * DMODEL, dst, xb);
  }
}

// Round 10
// 940.833 us; speedup vs baseline: 1.0223x; 1.0017x over previous
//
#include <hip/hip_runtime.h>

#define LNUM 4
#define DMODEL 1024
#define NHEAD 16
#define FDIM 4096
#define BATCH 4
#define SEQ 1024
#define HDIM 64
#define KBAND 8
#define MROWS (BATCH * SEQ)

typedef __attribute__((ext_vector_type(8))) __bf16 bf16x8;
typedef __attribute__((ext_vector_type(4))) float f32x4;
typedef __attribute__((ext_vector_type(8))) unsigned short u16x8;

__device__ __forceinline__ unsigned short f2bf(float f) {
  unsigned int u = __builtin_bit_cast(unsigned int, f);
  u = u + 0x7fffu + ((u >> 16) & 1u);
  return (unsigned short)(u >> 16);
}
__device__ __forceinline__ float bf2f(unsigned short h) {
  unsigned int u = ((unsigned int)h) << 16;
  return __builtin_bit_cast(float, u);
}

#define GLOAD16(gp, lp)                                                        \
  __builtin_amdgcn_global_load_lds(                                            \
      (const __attribute__((address_space(1))) void*)(gp),                     \
      (__attribute__((address_space(3))) void*)(lp), 16, 0, 0)

// ---------------- fp32 -> bf16 conversion -----------------------------------
__global__ __launch_bounds__(256) void cvt_bf16(const float* __restrict__ in,
                                                unsigned short* __restrict__ out,
                                                long n) {
  long i = ((long)blockIdx.x * 256 + threadIdx.x) * 4;
  if (i + 3 < n) {
    float4 v = *reinterpret_cast<const float4*>(in + i);
    ushort4 o;
    o.x = f2bf(v.x);
    o.y = f2bf(v.y);
    o.z = f2bf(v.z);
    o.w = f2bf(v.w);
    *reinterpret_cast<ushort4*>(out + i) = o;
  }
}

// ---------------- 128x128 bf16 GEMM, BK=64 single-buffer, C = A*W^T + bias --
// A: [M,K] bf16 rm. W: [N,K] bf16 rm. 256 thr = 4 waves (2x2), per-wave
// 64x64 out (acc 4x4 f32x4). Per iter: stage 8 gload_lds (32KB) -> sync ->
// 16 ds_read + 32 MFMA -> sync. vs R9's BK=32: half the barrier/drain
// frequency per FLOP (the R9 counters showed clean LDS+writes but per-iter
// drain pacing at ~1.1k cy for 80 cy of MFMA).
// Swizzle for 128B rows (8x16B granules): stored (row,g) holds source
// granule g ^ ((row>>1)&7); write side pre-swizzles the global source col
// (t-granule key (t>>4)&7, invariant under row+32 per instr); read quad =
// kgrp ^ ((fr>>1)&7) -> 16 lanes hit all 8 quads 2x = conflict-free (m136).
// Epilogue: R9's verified wave-private LDS transpose, full 64B-line stores.
// blockIdx.z = K-split (range [z*Ks,(z+1)*Ks)); Ks % 64 == 0.
// EPI: 0 = bf16 (+bias), 1 = bf16 (+bias, exact gelu),
//      2 = bf16 PARTIAL slab per z (bias only z==0).
template <int EPI>
__global__ __launch_bounds__(256, 3) void gemm128(const unsigned short* __restrict__ A,
                                                  const unsigned short* __restrict__ W,
                                                  const float* __restrict__ bias,
                                                  unsigned short* __restrict__ Cout,
                                                  int Ndim, int Kdim, int Ks) {
  __shared__ unsigned short SH[16384];  // As=SH[0:8192], Bs=SH[8192:16384]
  unsigned short* As = SH;
  unsigned short* Bs = SH + 8192;
  const int tid = threadIdx.x;
  const int wave = tid >> 6;
  const int lane = tid & 63;

  // bijective XCD chunked swizzle (m204), bm-fastest within chunk.
  const int gx = gridDim.x, gy = gridDim.y;
  const int nwg = gx * gy;
  const int lin = blockIdx.x + blockIdx.y * gx;
  const int q8 = nwg >> 3, r8 = nwg & 7;
  const int xcd = lin & 7, cidx = lin >> 3;
  const int cbase = (xcd < r8) ? xcd * (q8 + 1) : r8 * (q8 + 1) + (xcd - r8) * q8;
  const int swz = cbase + cidx;
  const int bm0 = (swz % gy) * 128;
  const int bn0 = (swz / gy) * 128;
  const int kz0 = blockIdx.z * Ks;

  // staging: tile 128r x 64k = 16KB/matrix = 256 thr x 4 instrs x 16B.
  // instr i, thread t: row = (t>>3) + i*32, LDS granule t&7;
  // source granule = (t&7) ^ ((t>>4)&7)  [key (row>>1)&7].
  const int r0 = tid >> 3;                               // 0..31
  const int c0 = (((tid & 7) ^ ((tid >> 4) & 7)) << 3);  // swizzled col elem
  const unsigned short* gA = A + (size_t)(bm0 + r0) * Kdim + kz0 + c0;
  const unsigned short* gB = W + (size_t)(bn0 + r0) * Kdim + kz0 + c0;
  const size_t rs32 = (size_t)32 * Kdim;

  f32x4 acc[4][4] = {};

  const int wr = (wave >> 1) * 64;  // wave row origin in tile
  const int wc = (wave & 1) * 64;   // wave col origin in tile
  const int fr = lane & 15;
  const int rkey = (fr >> 1) & 7;   // read-side XOR key

  const int nt = Ks >> 6;
  for (int t = 0; t < nt; ++t) {
#pragma unroll
    for (int i = 0; i < 4; ++i) {
      GLOAD16(gA + i * rs32, &As[i * 2048 + wave * 512]);
      GLOAD16(gB + i * rs32, &Bs[i * 2048 + wave * 512]);
    }
    gA += 64;
    gB += 64;
    __syncthreads();  // drains vmcnt(0): tile staged
#pragma unroll
    for (int ks = 0; ks < 2; ++ks) {
      const int kg0 = (lane >> 4) + 4 * ks;                 // granule 0..7
      const int kofs = ((kg0 ^ rkey) << 3);                 // swizzled elem
      bf16x8 af[4], bfr[4];
#pragma unroll
      for (int i = 0; i < 4; ++i)
        af[i] = *reinterpret_cast<const bf16x8*>(&As[(wr + i * 16 + fr) * 64 + kofs]);
#pragma unroll
      for (int j = 0; j < 4; ++j)
        bfr[j] = *reinterpret_cast<const bf16x8*>(&Bs[(wc + j * 16 + fr) * 64 + kofs]);
#pragma unroll
      for (int i = 0; i < 4; ++i)
#pragma unroll
        for (int j = 0; j < 4; ++j)
          acc[i][j] = __builtin_amdgcn_mfma_f32_16x16x32_bf16(af[i], bfr[j], acc[i][j], 0, 0, 0);
    }
    __syncthreads();  // reads done before next stage overwrites
  }

  // ---- transposed epilogue (R9-verified; LDS reused) ----
  // C/D layout: col = lane&15, row = (lane>>4)*4 + reg (m89/m91).
  const int rr = (lane >> 4) * 4;
  const int cc = lane & 15;
  const bool addb = (EPI != 2) || (blockIdx.z == 0);
  unsigned short* outZ =
      Cout + (EPI == 2 ? (size_t)blockIdx.z * ((size_t)gy * 128) * Ndim : 0);
  float bv[4];
#pragma unroll
  for (int j = 0; j < 4; ++j)
    bv[j] = addb ? bias[bn0 + wc + j * 16 + cc] : 0.0f;

  unsigned short* lt = SH + wave * 1280;  // 2560 B per wave (32 rows x 40 u16)
#pragma unroll
  for (int rh = 0; rh < 2; ++rh) {        // row half: rows rh*32..+31
#pragma unroll
    for (int cp = 0; cp < 2; ++cp) {      // col pair: cols cp*32..+31
#pragma unroll
      for (int ii = 0; ii < 2; ++ii)
#pragma unroll
        for (int jj = 0; jj < 2; ++jj)
#pragma unroll
          for (int r = 0; r < 4; ++r) {
            float v = acc[rh * 2 + ii][cp * 2 + jj][r] + bv[cp * 2 + jj];
            if (EPI == 1) v = 0.5f * v * (1.0f + erff(v * 0.70710678118654752f));
            lt[(ii * 16 + rr + r) * 40 + jj * 16 + cc] = f2bf(v);
          }
      asm volatile("s_waitcnt lgkmcnt(0)" ::: "memory");  // wave-local RAW
      const int rl = lane >> 1;            // local row 0..31
      const int chalf = (lane & 1) * 16;   // col sub-half (16 u16 = 32 B)
      u16x8 o0 = *reinterpret_cast<const u16x8*>(&lt[rl * 40 + chalf]);
      u16x8 o1 = *reinterpret_cast<const u16x8*>(&lt[rl * 40 + chalf + 8]);
      const int m = bm0 + wr + rh * 32 + rl;
      const int n0 = bn0 + wc + cp * 32 + chalf;
      unsigned short* dst = outZ + (size_t)m * Ndim + n0;
      *reinterpret_cast<u16x8*>(dst) = o0;
      *reinterpret_cast<u16x8*>(dst + 8) = o1;
      asm volatile("s_waitcnt lgkmcnt(0)" ::: "memory");  // reads done pre-overwrite
    }
  }
}

// ---------------- banded attention: one wave per (b,h,q), lane = d ----------
__global__ __launch_bounds__(256) void attn_band(const unsigned short* __restrict__ qkv,
                                                 unsigned short* __restrict__ outp) {
  const int gw = blockIdx.x * 4 + (threadIdx.x >> 6);
  const int lane = threadIdx.x & 63;
  const int q = gw & (SEQ - 1);
  const int bh = gw >> 10;
  const int h = bh & (NHEAD - 1);
  const int b = bh >> 4;
  const size_t row0 = (size_t)(b * SEQ + q);
  const size_t stride = 3 * DMODEL;
  const float qv = bf2f(qkv[row0 * stride + h * HDIM + lane]);

  float sc[KBAND];
  float mx = -1e30f;
#pragma unroll
  for (int jj = 0; jj < KBAND; ++jj) {
    const int j = q + jj;
    const int jc = (j < SEQ) ? j : (SEQ - 1);
    float kv = bf2f(qkv[(size_t)(b * SEQ + jc) * stride + DMODEL + h * HDIM + lane]);
    float p = qv * kv;
#pragma unroll
    for (int m = 32; m; m >>= 1) p += __shfl_xor(p, m);
    p *= 0.125f;
    p = (j < SEQ) ? p : -1e30f;
    sc[jj] = p;
    mx = fmaxf(mx, p);
  }
  float denom = 0.f;
  float ov = 0.f;
#pragma unroll
  for (int jj = 0; jj < KBAND; ++jj) {
    const int j = q + jj;
    const int jc = (j < SEQ) ? j : (SEQ - 1);
    float p = __expf(sc[jj] - mx);
    p = (j < SEQ) ? p : 0.f;
    denom += p;
    ov += p * bf2f(qkv[(size_t)(b * SEQ + jc) * stride + 2 * DMODEL + h * HDIM + lane]);
  }
  ov /= denom;
  outp[row0 * DMODEL + h * HDIM + lane] = f2bf(ov);
}

// ---------------- residual + nz-way bf16 split-K reduce + LayerNorm ---------
__global__ __launch_bounds__(256) void add_ln(const float* __restrict__ resid,
                                              const unsigned short* __restrict__ part,
                                              int nz,
                                              const float* __restrict__ gw,
                                              const float* __restrict__ gb,
                                              float* __restrict__ xf,
                                              unsigned short* __restrict__ xb) {
  const int row = blockIdx.x;
  const int tid = threadIdx.x;
  const size_t slab = (size_t)MROWS * DMODEL;
  const float* rp = resid + (size_t)row * DMODEL;
  const unsigned short* pp = part + (size_t)row * DMODEL;
  float v[4];
  float s = 0.f, s2 = 0.f;
#pragma unroll
  for (int i = 0; i < 4; ++i) {
    const int idx = tid + i * 256;
    float a = rp[idx];
    for (int z = 0; z < nz; ++z) a += bf2f(pp[z * slab + idx]);
    v[i] = a;
    s += a;
    s2 += a * a;
  }
#pragma unroll
  for (int m = 32; m; m >>= 1) {
    s += __shfl_xor(s, m);
    s2 += __shfl_xor(s2, m);
  }
  __shared__ float wsm[8];
  const int wave = tid >> 6, lane = tid & 63;
  if (lane == 0) {
    wsm[wave] = s;
    wsm[4 + wave] = s2;
  }
  __syncthreads();
  s = wsm[0] + wsm[1] + wsm[2] + wsm[3];
  s2 = wsm[4] + wsm[5] + wsm[6] + wsm[7];
  const float mean = s * (1.f / DMODEL);
  const float var = s2 * (1.f / DMODEL) - mean * mean;
  const float rstd = rsqrtf(var + 1e-5f);
#pragma unroll
  for (int i = 0; i < 4; ++i) {
    const int idx = tid + i * 256;
    const float y = (v[i] - mean) * rstd * gw[idx] + gb[idx];
    xf[(size_t)row * DMODEL + idx] = y;
    xb[(size_t)row * DMODEL + idx] = f2bf(y);
  }
}

extern "C" void kernel_launch(void* const* d_in, const int* in_sizes, int n_in,
                              void* d_out, int out_size, void* d_ws, size_t ws_size,
                              hipStream_t stream) {
  const float* src  = (const float*)d_in[0];
  const float* Wqkv = (const float*)d_in[1];
  const float* bqkv = (const float*)d_in[2];
  const float* Wo   = (const float*)d_in[3];
  const float* bo   = (const float*)d_in[4];
  const float* W1   = (const float*)d_in[5];
  const float* b1   = (const float*)d_in[6];
  const float* W2   = (const float*)d_in[7];
  const float* b2   = (const float*)d_in[8];
  const float* ln1w = (const float*)d_in[9];
  const float* ln1b = (const float*)d_in[10];
  const float* ln2w = (const float*)d_in[11];
  const float* ln2b = (const float*)d_in[12];
  float* out = (float*)d_out;

  // workspace carve-up (~184 MB of 209.7 MB)
  char* p = (char*)d_ws;
  unsigned short* wqkv_b = (unsigned short*)p; p += (size_t)LNUM * 3072 * 1024 * 2;
  unsigned short* wo_b   = (unsigned short*)p; p += (size_t)LNUM * 1024 * 1024 * 2;
  unsigned short* w1_b   = (unsigned short*)p; p += (size_t)LNUM * 4096 * 1024 * 2;
  unsigned short* w2_b   = (unsigned short*)p; p += (size_t)LNUM * 1024 * 4096 * 2;
  float*          xf     = (float*)p;          p += (size_t)MROWS * DMODEL * 4;
  unsigned short* xb     = (unsigned short*)p; p += (size_t)MROWS * DMODEL * 2;
  // region R: [qkvb 24MB | aob 8MB] aliased by [hb 32MB], then part 4x8MB bf16
  char* R = p;
  unsigned short* qkvb = (unsigned short*)R;
  unsigned short* aob  = (unsigned short*)(R + (size_t)MROWS * 3 * DMODEL * 2);
  unsigned short* hb   = (unsigned short*)R;
  unsigned short* part = (unsigned short*)(R + (size_t)MROWS * 4096 * 2);
  p = R + (size_t)MROWS * 4096 * 2 + (size_t)4 * MROWS * DMODEL * 2;
  if (ws_size < (size_t)(p - (char*)d_ws)) return;

  cvt_bf16<<<(long)LNUM * 3072 * 1024 / 1024, 256, 0, stream>>>(Wqkv, wqkv_b, (long)LNUM * 3072 * 1024);
  cvt_bf16<<<(long)LNUM * 1024 * 1024 / 1024, 256, 0, stream>>>(Wo, wo_b, (long)LNUM * 1024 * 1024);
  cvt_bf16<<<(long)LNUM * 4096 * 1024 / 1024, 256, 0, stream>>>(W1, w1_b, (long)LNUM * 4096 * 1024);
  cvt_bf16<<<(long)LNUM * 1024 * 4096 / 1024, 256, 0, stream>>>(W2, w2_b, (long)LNUM * 1024 * 4096);
  cvt_bf16<<<(long)MROWS * DMODEL / 1024, 256, 0, stream>>>(src, xb, (long)MROWS * DMODEL);

  for (int l = 0; l < LNUM; ++l) {
    // QKV: [4096,1024] x [3072,1024]^T -> bf16 [4096,3072]; 768 blk (3/CU)
    gemm128<0><<<dim3(3072 / 128, MROWS / 128, 1), 256, 0, stream>>>(
        xb, wqkv_b + (size_t)l * 3072 * 1024, bqkv + l * 3072, qkvb, 3072, 1024, 1024);
    attn_band<<<(BATCH * NHEAD * SEQ) / 4, 256, 0, stream>>>(qkvb, aob);
    // Wo: split-K=2 (Ks=512) -> bf16 partials; 512 blk (2/CU)
    gemm128<2><<<dim3(1024 / 128, MROWS / 128, 2), 256, 0, stream>>>(
        aob, wo_b + (size_t)l * 1024 * 1024, bo + l * 1024, part, 1024, 1024, 512);
    add_ln<<<MROWS, 256, 0, stream>>>(l == 0 ? src : xf, part, 2,
                                      ln1w + l * DMODEL, ln1b + l * DMODEL, xf, xb);
    // W1 + gelu: -> bf16 [4096,4096]; 1024 blk (4/CU)
    gemm128<1><<<dim3(FDIM / 128, MROWS / 128, 1), 256, 0, stream>>>(
        xb, w1_b + (size_t)l * 4096 * 1024, b1 + l * FDIM, hb, FDIM, 1024, 1024);
    // W2: split-K=4 (Ks=1024) -> bf16 partials; 1024 blk (4/CU)
    gemm128<2><<<dim3(1024 / 128, MROWS / 128, 4), 256, 0, stream>>>(
        hb, w2_b + (size_t)l * 1024 * 4096, b2 + l * 1024, part, 1024, 4096, 1024);
    float* dst = (l == LNUM - 1) ? out : xf;
    add_ln<<<MROWS, 256, 0, stream>>>(xf, part, 4,
                                      ln2w + l * DMODEL, ln2b + l * DMODEL, dst, xb);
  }
}